// Round 1
// 1674.040 us; speedup vs baseline: 4.7916x; 4.7916x over previous
//
#include <hip/hip_runtime.h>
#include <hip/hip_bf16.h>
#include <cmath>

typedef __bf16 bf16;
typedef bf16 bf16x4 __attribute__((ext_vector_type(4)));
typedef float f32x4 __attribute__((ext_vector_type(4)));
typedef short short8 __attribute__((ext_vector_type(8)));

#define S_LEN 4096
#define EMB   2048
#define NH    16
#define NKV   4
#define HD    128
#define WIN   2048

// ---------------------------------------------------------------------------
// Naive-but-tiled pure-VALU f32 GEMM: C[M,N] = A[M,K] * B[K,N].
// Correctness anchor (no MFMA). 64x64 tile, BK=16, 256 thr, 4x4 per thread.
// ---------------------------------------------------------------------------
template<bool A_BF16, bool C_BF16>
__global__ __launch_bounds__(256)
void gemm_naive(const void* __restrict__ Ap, const float* __restrict__ B,
                void* __restrict__ Cp, int M, int N, int K)
{
    __shared__ float As[16][68];   // [k][m] (transposed on stage)
    __shared__ float Bs[16][68];   // [k][n]
    const int tid = threadIdx.x;
    const int m0 = blockIdx.y * 64, n0 = blockIdx.x * 64;
    const int ty = tid >> 4, tx = tid & 15;

    float acc[4][4];
    #pragma unroll
    for (int i = 0; i < 4; i++)
        #pragma unroll
        for (int j = 0; j < 4; j++) acc[i][j] = 0.f;

    const int aml = tid >> 2, akq = (tid & 3) * 4;   // A stage: 64 rows x 16 k
    const int bkl = tid >> 4, bnq = (tid & 15) * 4;  // B stage: 16 k x 64 n

    for (int k0 = 0; k0 < K; k0 += 16) {
        if (A_BF16) {
            const bf16* A = (const bf16*)Ap;
            bf16x4 a = *(const bf16x4*)(A + (long)(m0 + aml) * K + k0 + akq);
            #pragma unroll
            for (int i = 0; i < 4; i++) As[akq + i][aml] = (float)a[i];
        } else {
            const float* A = (const float*)Ap;
            f32x4 a = *(const f32x4*)(A + (long)(m0 + aml) * K + k0 + akq);
            #pragma unroll
            for (int i = 0; i < 4; i++) As[akq + i][aml] = a[i];
        }
        {
            f32x4 b = *(const f32x4*)(B + (long)(k0 + bkl) * N + n0 + bnq);
            *(f32x4*)&Bs[bkl][bnq] = b;
        }
        __syncthreads();

        #pragma unroll
        for (int kk = 0; kk < 16; kk++) {
            f32x4 a4 = *(const f32x4*)&As[kk][ty * 4];
            f32x4 b4 = *(const f32x4*)&Bs[kk][tx * 4];
            #pragma unroll
            for (int i = 0; i < 4; i++)
                #pragma unroll
                for (int j = 0; j < 4; j++)
                    acc[i][j] += a4[i] * b4[j];
        }
        __syncthreads();
    }

    #pragma unroll
    for (int i = 0; i < 4; i++)
        #pragma unroll
        for (int j = 0; j < 4; j++) {
            long row = m0 + ty * 4 + i, col = n0 + tx * 4 + j;
            if (C_BF16) ((bf16*)Cp)[row * N + col] = (bf16)acc[i][j];
            else        ((float*)Cp)[row * N + col] = acc[i][j];
        }
}

// ---------------------------------------------------------------------------
// In-place RoPE on bf16 [S][nh*128] (f32 math). position_ids == arange(S).
// ---------------------------------------------------------------------------
__global__ __launch_bounds__(256)
void rope_k(bf16* __restrict__ X, int nh)
{
    int idx = blockIdx.x * 256 + threadIdx.x;
    int i = idx & 63;
    int h = (idx >> 6) % nh;
    int s = idx / (64 * nh);
    bf16* p = X + (long)s * (nh * HD) + h * HD + i;
    float x1 = (float)p[0];
    float x2 = (float)p[64];
    float f = exp2f((float)i * (-13.287712379549449f / 64.0f)); // 10000^(-i/64)
    float ang = (float)s * f;
    float sn, cs;
    sincosf(ang, &sn, &cs);
    p[0]  = (bf16)(x1 * cs - x2 * sn);
    p[64] = (bf16)(x2 * cs + x1 * sn);
}

// ---------------------------------------------------------------------------
// Transpose V: Vb[S][NKV*HD] -> Vt[NKV*HD][S] (row index = kvh*128 + d).
// Small (8 MiB traffic) — enables contiguous ds_read_b128 B-frags in PV.
// ---------------------------------------------------------------------------
__global__ __launch_bounds__(256)
void transpose_v(const bf16* __restrict__ V, bf16* __restrict__ Vt)
{
    __shared__ bf16 t[32][33];
    const int s0 = blockIdx.x * 32;
    const int d0 = blockIdx.y * 32;
    const int tx = threadIdx.x & 31, ty = threadIdx.x >> 5; // ty 0..7
    #pragma unroll
    for (int k = 0; k < 4; k++)
        t[ty + 8 * k][tx] = V[(long)(s0 + ty + 8 * k) * (NKV * HD) + d0 + tx];
    __syncthreads();
    #pragma unroll
    for (int k = 0; k < 4; k++) {
        int drow = d0 + ty + 8 * k;
        Vt[(long)drow * S_LEN + s0 + tx] = t[tx][ty + 8 * k];
    }
}

// ---------------------------------------------------------------------------
// MFMA flash attention (sliding-window causal, GQA).
// Grid (S/64, NH), 256 threads = 4 waves. Block = 64 q-rows of one q-head;
// wave w owns q-rows qw..qw+15. K/V tiles of 64 keys staged in swizzled LDS.
// mfma_f32_16x16x32_bf16 everywhere; online softmax in f32.
//   A-frag: row = lane&15, k = (lane>>4)*8 + i (contiguous 8)
//   B-frag: col = lane&15, k = (lane>>4)*8 + i (contiguous 8)
//   C:      row = (lane>>4)*4 + reg, col = lane&15   [verified m89]
// LDS swizzle byte ^= ((row&7)<<4) on both write and read (16B-granular).
// P (C-layout) -> A-layout fixed via per-wave padded LDS round-trip.
// ---------------------------------------------------------------------------
__global__ __launch_bounds__(256)
void attn_mfma(const bf16* __restrict__ Qb, const bf16* __restrict__ Kb,
               const bf16* __restrict__ Vt, bf16* __restrict__ Ob)
{
    __shared__ bf16 Kl[64 * 128];   // [key][d],  row 256B, byte ^= ((key&7)<<4)
    __shared__ bf16 Vl[128 * 64];   // [d][key],  row 128B, byte ^= ((d&7)<<4)
    __shared__ bf16 Pl[4][16][72];  // per-wave P tile, padded 64->72

    const int qb  = blockIdx.x;
    const int h   = blockIdx.y;
    const int kvh = h >> 2;
    const int q0  = qb * 64;
    const int tid = threadIdx.x;
    const int w   = tid >> 6;
    const int l16 = tid & 15;
    const int lq4 = (tid & 63) >> 4;
    const int qw  = q0 + w * 16;

    // Q fragments for this wave's 16 rows (4 k-chunks over d=128), kept in VGPRs.
    short8 aQ[4];
    {
        const bf16* qp = Qb + (long)(qw + l16) * EMB + h * HD + lq4 * 8;
        #pragma unroll
        for (int c = 0; c < 4; c++) aQ[c] = *(const short8*)(qp + c * 32);
    }

    const f32x4 fzero = {0.f, 0.f, 0.f, 0.f};
    float m[4], lsum[4];
    f32x4 accO[8];
    #pragma unroll
    for (int r = 0; r < 4; r++) { m[r] = -1e30f; lsum[r] = 0.f; }
    #pragma unroll
    for (int dt = 0; dt < 8; dt++) accO[dt] = fzero;

    const int jb0 = (q0 >= WIN) ? q0 - WIN : 0;
    char* KlB = (char*)Kl;
    char* VlB = (char*)Vl;

    for (int jb = jb0; jb <= q0; jb += 64) {
        __syncthreads();   // protect LDS from previous iteration's readers
        // Stage K tile [64 keys][128 d] and V tile [128 d][64 keys] (16B chunks).
        #pragma unroll
        for (int it = 0; it < 4; it++) {
            int c = it * 256 + tid;
            int key = c >> 4, d0 = (c & 15) * 8;
            short8 kv = *(const short8*)(Kb + (long)(jb + key) * (NKV * HD) + kvh * HD + d0);
            *(short8*)(KlB + ((key * 256 + d0 * 2) ^ ((key & 7) << 4))) = kv;
            int d = c >> 3, k0 = (c & 7) * 8;
            short8 vv = *(const short8*)(Vt + ((long)kvh * HD + d) * S_LEN + jb + k0);
            *(short8*)(VlB + ((d * 128 + k0 * 2) ^ ((d & 7) << 4))) = vv;
        }
        __syncthreads();

        // --- QK^T: 16 q-rows x 64 keys, 4 col-tiles x 4 k-chunks of MFMA ---
        f32x4 s[4];
        #pragma unroll
        for (int jt = 0; jt < 4; jt++) {
            f32x4 acc = fzero;
            int key = jt * 16 + l16;
            #pragma unroll
            for (int c = 0; c < 4; c++) {
                short8 bk = *(const short8*)(
                    KlB + ((key * 256 + c * 64 + lq4 * 16) ^ ((key & 7) << 4)));
                acc = __builtin_amdgcn_mfma_f32_16x16x32_bf16(aQ[c], bk, acc, 0, 0, 0);
            }
            s[jt] = acc;
        }

        // --- scale + sliding-window causal mask + row max (over 16 lanes) ---
        float tmax[4];
        #pragma unroll
        for (int r = 0; r < 4; r++) tmax[r] = -1e30f;
        #pragma unroll
        for (int jt = 0; jt < 4; jt++) {
            int j = jb + jt * 16 + l16;
            #pragma unroll
            for (int r = 0; r < 4; r++) {
                int qi = qw + lq4 * 4 + r;
                float sv = s[jt][r] * 0.08838834764831845f;  // 1/sqrt(128)
                if (j > qi || j < qi - WIN) sv = -1e30f;
                s[jt][r] = sv;
                tmax[r] = fmaxf(tmax[r], sv);
            }
        }
        #pragma unroll
        for (int r = 0; r < 4; r++) {
            float t = tmax[r];
            t = fmaxf(t, __shfl_xor(t, 1, 64));
            t = fmaxf(t, __shfl_xor(t, 2, 64));
            t = fmaxf(t, __shfl_xor(t, 4, 64));
            t = fmaxf(t, __shfl_xor(t, 8, 64));
            tmax[r] = t;
        }

        // --- online softmax update ---
        float alpha[4];
        #pragma unroll
        for (int r = 0; r < 4; r++) {
            float mn = fmaxf(m[r], tmax[r]);
            alpha[r] = __expf(m[r] - mn);
            m[r] = mn;
        }
        float rsum[4] = {0.f, 0.f, 0.f, 0.f};
        #pragma unroll
        for (int jt = 0; jt < 4; jt++)
            #pragma unroll
            for (int r = 0; r < 4; r++) {
                float pv = __expf(s[jt][r] - m[r]);   // masked: exp(-1e30-..)=0
                bf16 pb = (bf16)pv;
                Pl[w][lq4 * 4 + r][jt * 16 + l16] = pb;
                rsum[r] += (float)pb;   // denominator from ROUNDED p (consistency)
            }
        #pragma unroll
        for (int r = 0; r < 4; r++) {
            float t = rsum[r];
            t += __shfl_xor(t, 1, 64);
            t += __shfl_xor(t, 2, 64);
            t += __shfl_xor(t, 4, 64);
            t += __shfl_xor(t, 8, 64);
            lsum[r] = lsum[r] * alpha[r] + t;
        }
        #pragma unroll
        for (int dt = 0; dt < 8; dt++)
            #pragma unroll
            for (int r = 0; r < 4; r++)
                accO[dt][r] *= alpha[r];

        // --- PV: O[16 x 128] += P[16 x 64] * V[64 x 128] ---
        #pragma unroll
        for (int kc = 0; kc < 2; kc++) {
            short8 ap = *(const short8*)&Pl[w][l16][kc * 32 + lq4 * 8];
            #pragma unroll
            for (int dt = 0; dt < 8; dt++) {
                int d = dt * 16 + l16;
                short8 bv = *(const short8*)(
                    VlB + ((d * 128 + kc * 64 + lq4 * 16) ^ ((d & 7) << 4)));
                accO[dt] = __builtin_amdgcn_mfma_f32_16x16x32_bf16(ap, bv, accO[dt], 0, 0, 0);
            }
        }
    }

    // --- epilogue: normalize and store ---
    #pragma unroll
    for (int r = 0; r < 4; r++) {
        float inv = 1.0f / lsum[r];
        int qi = qw + lq4 * 4 + r;
        bf16* op = Ob + (long)qi * EMB + h * HD + l16;
        #pragma unroll
        for (int dt = 0; dt < 8; dt++)
            op[dt * 16] = (bf16)(accO[dt][r] * inv);
    }
}

// ---------------------------------------------------------------------------
extern "C" void kernel_launch(void* const* d_in, const int* in_sizes, int n_in,
                              void* d_out, int out_size, void* d_ws, size_t ws_size,
                              hipStream_t stream)
{
    (void)out_size; (void)ws_size;
    // Robust input identification by in_sizes pattern:
    //   q/k/v = 8388608 elems, pos = 4096, wq/wo = 4194304, wk/wv = 1048576.
    // Dict order -> bigs=[q,k,v], w4=[wq,wo]; alphabetical (pos at index 1)
    // -> bigs=[k,q,v], w4=[wo,wq]. wk precedes wv in both.
    int idx_pos = -1;
    for (int i = 0; i < n_in; i++)
        if (in_sizes[i] == 4096) { idx_pos = i; break; }
    int bigs[3] = {0, 1, 2}, w4[2] = {4, 6}, w1[2] = {5, 5};
    int nb = 0, n4 = 0, n1 = 0;
    for (int i = 0; i < n_in; i++) {
        if (in_sizes[i] == 8388608 && nb < 3) bigs[nb++] = i;
        else if (in_sizes[i] == 4194304 && n4 < 2) w4[n4++] = i;
        else if (in_sizes[i] == 1048576 && n1 < 2) w1[n1++] = i;
    }
    bool alpha = (idx_pos == 1);
    int iq  = alpha ? bigs[1] : bigs[0];
    int ik  = alpha ? bigs[0] : bigs[1];
    int iv  = bigs[2];
    int iwq = alpha ? w4[1] : w4[0];
    int iwo = alpha ? w4[0] : w4[1];
    int iwk = w1[0];
    int iwv = w1[1];
    const float* query = (const float*)d_in[iq];
    const float* key   = (const float*)d_in[ik];
    const float* value = (const float*)d_in[iv];
    const float* wq = (const float*)d_in[iwq];
    const float* wk = (const float*)d_in[iwk];
    const float* wv = (const float*)d_in[iwv];
    const float* wo = (const float*)d_in[iwo];

    // Layout: Qb in d_out (dead until final GEMM overwrites it).
    // ws: Kb[0:4M) Vb[4:8M) Ob[8:24M) Vt[24:28M)  (ws_size ~36 MiB).
    bf16* Qb = (bf16*)d_out;
    char* ws = (char*)d_ws;
    bf16* Kb = (bf16*)(ws);
    bf16* Vb = (bf16*)(ws + (4u  << 20));
    bf16* Ob = (bf16*)(ws + (8u  << 20));
    bf16* Vt = (bf16*)(ws + (24u << 20));

    dim3 blk(256);
    gemm_naive<false, true><<<dim3(EMB / 64, S_LEN / 64), blk, 0, stream>>>(
        query, wq, Qb, S_LEN, EMB, EMB);
    gemm_naive<false, true><<<dim3((NKV * HD) / 64, S_LEN / 64), blk, 0, stream>>>(
        key, wk, Kb, S_LEN, NKV * HD, EMB);
    gemm_naive<false, true><<<dim3((NKV * HD) / 64, S_LEN / 64), blk, 0, stream>>>(
        value, wv, Vb, S_LEN, NKV * HD, EMB);
    rope_k<<<(S_LEN * NH * 64) / 256, blk, 0, stream>>>(Qb, NH);
    rope_k<<<(S_LEN * NKV * 64) / 256, blk, 0, stream>>>(Kb, NKV);
    transpose_v<<<dim3(S_LEN / 32, (NKV * HD) / 32), blk, 0, stream>>>(Vb, Vt);
    attn_mfma<<<dim3(S_LEN / 64, NH), blk, 0, stream>>>(Qb, Kb, Vt, Ob);
    // Final projection overwrites d_out (Qb dead; A in ws, C in d_out).
    gemm_naive<true, false><<<dim3(EMB / 64, S_LEN / 64), blk, 0, stream>>>(
        Ob, wo, d_out, S_LEN, EMB, EMB);
}

// Round 3
// 751.688 us; speedup vs baseline: 10.6710x; 2.2270x over previous
//
#include <hip/hip_runtime.h>
#include <hip/hip_bf16.h>
#include <cmath>

typedef __bf16 bf16;
typedef bf16 bf16x4 __attribute__((ext_vector_type(4)));
typedef float f32x4 __attribute__((ext_vector_type(4)));
typedef short short8 __attribute__((ext_vector_type(8)));

#define S_LEN 4096
#define EMB   2048
#define NH    16
#define NKV   4
#define HD    128
#define WIN   2048

// ---------------------------------------------------------------------------
// Weight transpose+convert: W[K][N] f32 -> Wt[N][K] bf16. 32x32 LDS tiles.
// ---------------------------------------------------------------------------
__global__ __launch_bounds__(256)
void transpose_w(const float* __restrict__ W, bf16* __restrict__ Wt, int K, int N)
{
    __shared__ float t[32][33];
    const int k0 = blockIdx.x * 32, n0 = blockIdx.y * 32;
    const int tx = threadIdx.x & 31, ty = threadIdx.x >> 5;  // ty 0..7
    #pragma unroll
    for (int i = 0; i < 4; i++)
        t[ty + 8 * i][tx] = W[(long)(k0 + ty + 8 * i) * N + n0 + tx];
    __syncthreads();
    #pragma unroll
    for (int i = 0; i < 4; i++)
        Wt[(long)(n0 + ty + 8 * i) * K + k0 + tx] = (bf16)t[tx][ty + 8 * i];
}

// ---------------------------------------------------------------------------
// MFMA bf16 GEMM: C[M,N] = A[M,K] * Bt[N,K]^T, f32 accumulate.
// 128x128 tile, BK=32, 256 thr = 4 waves, each wave computes 64x64
// (4x4 frags of mfma_f32_16x16x32_bf16). A may be f32 (converted in staging)
// or bf16. Bt is pre-transposed bf16. LDS rows 64B, swizzle byte^=((row&7)<<4)
// applied identically on write and read (bijective; hand-verified).
//   A-frag: row = lane&15, k = (lane>>4)*8 + i     (8 contiguous)
//   B-frag: col = lane&15, k = (lane>>4)*8 + i
//   C:      row = (lane>>4)*4 + reg, col = lane&15  [verified m89]
// ---------------------------------------------------------------------------
template<bool A_BF16, bool C_BF16>
__global__ __launch_bounds__(256)
void gemm_mfma(const void* __restrict__ Ap, const bf16* __restrict__ Bt,
               void* __restrict__ Cp, int M, int N, int K)
{
    __shared__ __align__(16) bf16 As[128 * 32];   // [m][k]
    __shared__ __align__(16) bf16 Bs[128 * 32];   // [n][k]
    char* AsB = (char*)As;
    char* BsB = (char*)Bs;
    const int tid = threadIdx.x;
    const int n0 = blockIdx.x * 128, m0 = blockIdx.y * 128;
    const int w = tid >> 6;
    const int wm = (w >> 1) * 64, wn = (w & 1) * 64;
    const int l16 = tid & 15, lq4 = (tid & 63) >> 4;

    const f32x4 fz = {0.f, 0.f, 0.f, 0.f};
    f32x4 acc[4][4];
    #pragma unroll
    for (int i = 0; i < 4; i++)
        #pragma unroll
        for (int j = 0; j < 4; j++) acc[i][j] = fz;

    // staging: thread t covers LDS row t>>1 (m or n), k-half (t&1)*16
    const int sr = tid >> 1;
    const int sh = (tid & 1) * 16;
    const long arow = (long)(m0 + sr) * K;
    const long brow = (long)(n0 + sr) * K;
    const int wbase = sr * 64;
    const int swz = (sr & 7) << 4;

    for (int k0 = 0; k0 < K; k0 += 32) {
        __syncthreads();   // protect previous iteration's frag reads
        short8 av0, av1;
        if (A_BF16) {
            const bf16* A = (const bf16*)Ap;
            av0 = *(const short8*)(A + arow + k0 + sh);
            av1 = *(const short8*)(A + arow + k0 + sh + 8);
        } else {
            const float* A = (const float*)Ap;
            f32x4 a0 = *(const f32x4*)(A + arow + k0 + sh);
            f32x4 a1 = *(const f32x4*)(A + arow + k0 + sh + 4);
            f32x4 a2 = *(const f32x4*)(A + arow + k0 + sh + 8);
            f32x4 a3 = *(const f32x4*)(A + arow + k0 + sh + 12);
            bf16* p0 = (bf16*)&av0;
            bf16* p1 = (bf16*)&av1;
            #pragma unroll
            for (int i = 0; i < 4; i++) {
                p0[i]     = (bf16)a0[i];
                p0[4 + i] = (bf16)a1[i];
                p1[i]     = (bf16)a2[i];
                p1[4 + i] = (bf16)a3[i];
            }
        }
        short8 bv0 = *(const short8*)(Bt + brow + k0 + sh);
        short8 bv1 = *(const short8*)(Bt + brow + k0 + sh + 8);
        *(short8*)(AsB + ((wbase + sh * 2     ) ^ swz)) = av0;
        *(short8*)(AsB + ((wbase + sh * 2 + 16) ^ swz)) = av1;
        *(short8*)(BsB + ((wbase + sh * 2     ) ^ swz)) = bv0;
        *(short8*)(BsB + ((wbase + sh * 2 + 16) ^ swz)) = bv1;
        __syncthreads();

        short8 af[4], bfr[4];
        #pragma unroll
        for (int i = 0; i < 4; i++) {
            int mr = wm + i * 16 + l16;
            af[i]  = *(const short8*)(AsB + ((mr * 64 + lq4 * 16) ^ ((mr & 7) << 4)));
            int nr = wn + i * 16 + l16;
            bfr[i] = *(const short8*)(BsB + ((nr * 64 + lq4 * 16) ^ ((nr & 7) << 4)));
        }
        #pragma unroll
        for (int i = 0; i < 4; i++)
            #pragma unroll
            for (int j = 0; j < 4; j++)
                acc[i][j] = __builtin_amdgcn_mfma_f32_16x16x32_bf16(
                    af[i], bfr[j], acc[i][j], 0, 0, 0);
    }

    #pragma unroll
    for (int i = 0; i < 4; i++)
        #pragma unroll
        for (int r = 0; r < 4; r++) {
            long row = m0 + wm + i * 16 + lq4 * 4 + r;
            #pragma unroll
            for (int j = 0; j < 4; j++) {
                long col = n0 + wn + j * 16 + l16;
                if (C_BF16) ((bf16*)Cp)[row * N + col] = (bf16)acc[i][j][r];
                else        ((float*)Cp)[row * N + col] = acc[i][j][r];
            }
        }
}

// ---------------------------------------------------------------------------
// In-place RoPE on bf16 [S][nh*128] (f32 math). position_ids == arange(S).
// ---------------------------------------------------------------------------
__global__ __launch_bounds__(256)
void rope_k(bf16* __restrict__ X, int nh)
{
    int idx = blockIdx.x * 256 + threadIdx.x;
    int i = idx & 63;
    int h = (idx >> 6) % nh;
    int s = idx / (64 * nh);
    bf16* p = X + (long)s * (nh * HD) + h * HD + i;
    float x1 = (float)p[0];
    float x2 = (float)p[64];
    float f = exp2f((float)i * (-13.287712379549449f / 64.0f)); // 10000^(-i/64)
    float ang = (float)s * f;
    float sn, cs;
    sincosf(ang, &sn, &cs);
    p[0]  = (bf16)(x1 * cs - x2 * sn);
    p[64] = (bf16)(x2 * cs + x1 * sn);
}

// ---------------------------------------------------------------------------
// Transpose V: Vb[S][NKV*HD] -> Vt[NKV*HD][S] (row index = kvh*128 + d).
// ---------------------------------------------------------------------------
__global__ __launch_bounds__(256)
void transpose_v(const bf16* __restrict__ V, bf16* __restrict__ Vt)
{
    __shared__ bf16 t[32][33];
    const int s0 = blockIdx.x * 32;
    const int d0 = blockIdx.y * 32;
    const int tx = threadIdx.x & 31, ty = threadIdx.x >> 5; // ty 0..7
    #pragma unroll
    for (int k = 0; k < 4; k++)
        t[ty + 8 * k][tx] = V[(long)(s0 + ty + 8 * k) * (NKV * HD) + d0 + tx];
    __syncthreads();
    #pragma unroll
    for (int k = 0; k < 4; k++) {
        int drow = d0 + ty + 8 * k;
        Vt[(long)drow * S_LEN + s0 + tx] = t[tx][ty + 8 * k];
    }
}

// ---------------------------------------------------------------------------
// MFMA flash attention (sliding-window causal, GQA).
// Grid (S/64, NH), 256 threads = 4 waves. Block = 64 q-rows of one q-head;
// wave w owns q-rows qw..qw+15. K/V tiles of 64 keys staged in swizzled LDS.
// mfma_f32_16x16x32_bf16 everywhere; online softmax in f32.
// ---------------------------------------------------------------------------
__global__ __launch_bounds__(256)
void attn_mfma(const bf16* __restrict__ Qb, const bf16* __restrict__ Kb,
               const bf16* __restrict__ Vt, bf16* __restrict__ Ob)
{
    __shared__ bf16 Kl[64 * 128];   // [key][d],  row 256B, byte ^= ((key&7)<<4)
    __shared__ bf16 Vl[128 * 64];   // [d][key],  row 128B, byte ^= ((d&7)<<4)
    __shared__ bf16 Pl[4][16][72];  // per-wave P tile, padded 64->72

    const int qb  = blockIdx.x;
    const int h   = blockIdx.y;
    const int kvh = h >> 2;
    const int q0  = qb * 64;
    const int tid = threadIdx.x;
    const int w   = tid >> 6;
    const int l16 = tid & 15;
    const int lq4 = (tid & 63) >> 4;
    const int qw  = q0 + w * 16;

    short8 aQ[4];
    {
        const bf16* qp = Qb + (long)(qw + l16) * EMB + h * HD + lq4 * 8;
        #pragma unroll
        for (int c = 0; c < 4; c++) aQ[c] = *(const short8*)(qp + c * 32);
    }

    const f32x4 fzero = {0.f, 0.f, 0.f, 0.f};
    float m[4], lsum[4];
    f32x4 accO[8];
    #pragma unroll
    for (int r = 0; r < 4; r++) { m[r] = -1e30f; lsum[r] = 0.f; }
    #pragma unroll
    for (int dt = 0; dt < 8; dt++) accO[dt] = fzero;

    const int jb0 = (q0 >= WIN) ? q0 - WIN : 0;
    char* KlB = (char*)Kl;
    char* VlB = (char*)Vl;

    for (int jb = jb0; jb <= q0; jb += 64) {
        __syncthreads();
        #pragma unroll
        for (int it = 0; it < 4; it++) {
            int c = it * 256 + tid;
            int key = c >> 4, d0 = (c & 15) * 8;
            short8 kv = *(const short8*)(Kb + (long)(jb + key) * (NKV * HD) + kvh * HD + d0);
            *(short8*)(KlB + ((key * 256 + d0 * 2) ^ ((key & 7) << 4))) = kv;
            int d = c >> 3, k0 = (c & 7) * 8;
            short8 vv = *(const short8*)(Vt + ((long)kvh * HD + d) * S_LEN + jb + k0);
            *(short8*)(VlB + ((d * 128 + k0 * 2) ^ ((d & 7) << 4))) = vv;
        }
        __syncthreads();

        f32x4 s[4];
        #pragma unroll
        for (int jt = 0; jt < 4; jt++) {
            f32x4 acc = fzero;
            int key = jt * 16 + l16;
            #pragma unroll
            for (int c = 0; c < 4; c++) {
                short8 bk = *(const short8*)(
                    KlB + ((key * 256 + c * 64 + lq4 * 16) ^ ((key & 7) << 4)));
                acc = __builtin_amdgcn_mfma_f32_16x16x32_bf16(aQ[c], bk, acc, 0, 0, 0);
            }
            s[jt] = acc;
        }

        float tmax[4];
        #pragma unroll
        for (int r = 0; r < 4; r++) tmax[r] = -1e30f;
        #pragma unroll
        for (int jt = 0; jt < 4; jt++) {
            int j = jb + jt * 16 + l16;
            #pragma unroll
            for (int r = 0; r < 4; r++) {
                int qi = qw + lq4 * 4 + r;
                float sv = s[jt][r] * 0.08838834764831845f;  // 1/sqrt(128)
                if (j > qi || j < qi - WIN) sv = -1e30f;
                s[jt][r] = sv;
                tmax[r] = fmaxf(tmax[r], sv);
            }
        }
        #pragma unroll
        for (int r = 0; r < 4; r++) {
            float t = tmax[r];
            t = fmaxf(t, __shfl_xor(t, 1, 64));
            t = fmaxf(t, __shfl_xor(t, 2, 64));
            t = fmaxf(t, __shfl_xor(t, 4, 64));
            t = fmaxf(t, __shfl_xor(t, 8, 64));
            tmax[r] = t;
        }

        float alpha[4];
        #pragma unroll
        for (int r = 0; r < 4; r++) {
            float mn = fmaxf(m[r], tmax[r]);
            alpha[r] = __expf(m[r] - mn);
            m[r] = mn;
        }
        float rsum[4] = {0.f, 0.f, 0.f, 0.f};
        #pragma unroll
        for (int jt = 0; jt < 4; jt++)
            #pragma unroll
            for (int r = 0; r < 4; r++) {
                float pv = __expf(s[jt][r] - m[r]);
                bf16 pb = (bf16)pv;
                Pl[w][lq4 * 4 + r][jt * 16 + l16] = pb;
                rsum[r] += (float)pb;
            }
        #pragma unroll
        for (int r = 0; r < 4; r++) {
            float t = rsum[r];
            t += __shfl_xor(t, 1, 64);
            t += __shfl_xor(t, 2, 64);
            t += __shfl_xor(t, 4, 64);
            t += __shfl_xor(t, 8, 64);
            lsum[r] = lsum[r] * alpha[r] + t;
        }
        #pragma unroll
        for (int dt = 0; dt < 8; dt++)
            #pragma unroll
            for (int r = 0; r < 4; r++)
                accO[dt][r] *= alpha[r];

        #pragma unroll
        for (int kc = 0; kc < 2; kc++) {
            short8 ap = *(const short8*)&Pl[w][l16][kc * 32 + lq4 * 8];
            #pragma unroll
            for (int dt = 0; dt < 8; dt++) {
                int d = dt * 16 + l16;
                short8 bv = *(const short8*)(
                    VlB + ((d * 128 + kc * 64 + lq4 * 16) ^ ((d & 7) << 4)));
                accO[dt] = __builtin_amdgcn_mfma_f32_16x16x32_bf16(ap, bv, accO[dt], 0, 0, 0);
            }
        }
    }

    #pragma unroll
    for (int r = 0; r < 4; r++) {
        float inv = 1.0f / lsum[r];
        int qi = qw + lq4 * 4 + r;
        bf16* op = Ob + (long)qi * EMB + h * HD + l16;
        #pragma unroll
        for (int dt = 0; dt < 8; dt++)
            op[dt * 16] = (bf16)(accO[dt][r] * inv);
    }
}

// ---------------------------------------------------------------------------
extern "C" void kernel_launch(void* const* d_in, const int* in_sizes, int n_in,
                              void* d_out, int out_size, void* d_ws, size_t ws_size,
                              hipStream_t stream)
{
    (void)out_size; (void)ws_size;
    int idx_pos = -1;
    for (int i = 0; i < n_in; i++)
        if (in_sizes[i] == 4096) { idx_pos = i; break; }
    int bigs[3] = {0, 1, 2}, w4[2] = {4, 6}, w1[2] = {5, 5};
    int nb = 0, n4 = 0, n1 = 0;
    for (int i = 0; i < n_in; i++) {
        if (in_sizes[i] == 8388608 && nb < 3) bigs[nb++] = i;
        else if (in_sizes[i] == 4194304 && n4 < 2) w4[n4++] = i;
        else if (in_sizes[i] == 1048576 && n1 < 2) w1[n1++] = i;
    }
    bool alpha = (idx_pos == 1);
    int iq  = alpha ? bigs[1] : bigs[0];
    int ik  = alpha ? bigs[0] : bigs[1];
    int iv  = bigs[2];
    int iwq = alpha ? w4[1] : w4[0];
    int iwo = alpha ? w4[0] : w4[1];
    int iwk = w1[0];
    int iwv = w1[1];
    const float* query = (const float*)d_in[iq];
    const float* key   = (const float*)d_in[ik];
    const float* value = (const float*)d_in[iv];
    const float* wq = (const float*)d_in[iwq];
    const float* wk = (const float*)d_in[iwk];
    const float* wv = (const float*)d_in[iwv];
    const float* wo = (const float*)d_in[iwo];

    // Workspace lifetimes (peak 28 MiB):
    //   Kb [0,4M)  Vb [4,8M)  Ob [8,24M)  Vt [24,28M)
    //   wqT [8,16M)   (dead before Ob written)
    //   wkT [24,26M), wvT [26,28M) (dead before Vt written)
    //   woT [0,8M)    (written after Kb/Vb dead)
    bf16* Qb = (bf16*)d_out;                 // d_out[0:16M), dead before final GEMM
    char* ws = (char*)d_ws;
    bf16* Kb  = (bf16*)(ws);
    bf16* Vb  = (bf16*)(ws + (4u  << 20));
    bf16* Ob  = (bf16*)(ws + (8u  << 20));
    bf16* wqT = (bf16*)(ws + (8u  << 20));
    bf16* Vt  = (bf16*)(ws + (24u << 20));
    bf16* wkT = (bf16*)(ws + (24u << 20));
    bf16* wvT = (bf16*)(ws + (26u << 20));
    bf16* woT = (bf16*)(ws);

    dim3 blk(256);
    transpose_w<<<dim3(EMB / 32, EMB / 32), blk, 0, stream>>>(wq, wqT, EMB, EMB);
    transpose_w<<<dim3(EMB / 32, (NKV * HD) / 32), blk, 0, stream>>>(wk, wkT, EMB, NKV * HD);
    transpose_w<<<dim3(EMB / 32, (NKV * HD) / 32), blk, 0, stream>>>(wv, wvT, EMB, NKV * HD);

    gemm_mfma<false, true><<<dim3(EMB / 128, S_LEN / 128), blk, 0, stream>>>(
        query, wqT, Qb, S_LEN, EMB, EMB);
    gemm_mfma<false, true><<<dim3((NKV * HD) / 128, S_LEN / 128), blk, 0, stream>>>(
        key, wkT, Kb, S_LEN, NKV * HD, EMB);
    gemm_mfma<false, true><<<dim3((NKV * HD) / 128, S_LEN / 128), blk, 0, stream>>>(
        value, wvT, Vb, S_LEN, NKV * HD, EMB);

    rope_k<<<(S_LEN * NH * 64) / 256, blk, 0, stream>>>(Qb, NH);
    rope_k<<<(S_LEN * NKV * 64) / 256, blk, 0, stream>>>(Kb, NKV);
    transpose_v<<<dim3(S_LEN / 32, (NKV * HD) / 32), blk, 0, stream>>>(Vb, Vt);
    attn_mfma<<<dim3(S_LEN / 64, NH), blk, 0, stream>>>(Qb, Kb, Vt, Ob);

    transpose_w<<<dim3((NH * HD) / 32, EMB / 32), blk, 0, stream>>>(wo, woT, NH * HD, EMB);
    gemm_mfma<true, false><<<dim3(EMB / 128, S_LEN / 128), blk, 0, stream>>>(
        Ob, woT, d_out, S_LEN, EMB, EMB);
}